// Round 5
// baseline (331.732 us; speedup 1.0000x reference)
//
#include <hip/hip_runtime.h>
#include <hip/hip_bf16.h>
#include <stdint.h>

namespace {
constexpr int B = 128;
constexpr int N = 4096;
constexpr int S = 32;
constexpr int P = 64;
constexpr int D = 128;
constexpr int K = 384;          // 3*D
constexpr int KS = K / 32;      // 12 MFMA k-steps
constexpr int ROWPAD = 196;     // dwords per LDS activation row (192 used + 4 pad)
constexpr int PM_BLOCKS = (B * P) / 32;   // 256 (32 rows/block)
constexpr int ARM_BLOCKS = (2 * B) / 16;  // 16  (16 instances/block)
}

typedef __attribute__((ext_vector_type(8))) short short8;  // 8 bf16 (4 VGPRs)
typedef __attribute__((ext_vector_type(4))) float f32x4;   // MFMA C/D

// ---- bf16 helpers (RNE) ----
__device__ __forceinline__ uint32_t f2bf(float f) {        // scalar RNE
    union { float f; uint32_t u; } v; v.f = f;
    return (v.u + 0x7FFFu + ((v.u >> 16) & 1u)) >> 16;
}
__device__ __forceinline__ uint32_t pack2(float x, float y) {
    // HW packed cvt on gfx950 (v_cvt_pk_bf16_f32), RNE — same result as f2bf pair
    union { __hip_bfloat162 h; uint32_t u; } cv;
    cv.h = __float22bfloat162_rn(make_float2(x, y));
    return cv.u;
}

// Build a B-fragment in-register from raw fp32 W[K,D]:
// lane (q,n16) holds k = ks*32+q*8 .. +7 at column `col` (8 column-strided
// dword loads, coalesced 64B across n16, L2-resident).
__device__ __forceinline__ short8 load_bfrag(const float* __restrict__ W,
                                             int ks, int q, int col) {
    const float* p = W + (size_t)((ks * 32 + q * 8) * D + col);
    union { uint32_t u[4]; short8 s; } cv;
    #pragma unroll
    for (int jj = 0; jj < 4; ++jj)
        cv.u[jj] = pack2(p[(2 * jj) * D], p[(2 * jj + 1) * D]);
    return cv.s;
}

// Single fused kernel.
// Blocks 0..255: pm_emb GEMM, 32 rows x 128 cols per block (2 m-tiles,
//   B-fragments reused across m-tiles). Blocks 256..271: arm embeddings,
//   16 (b,arm) instances per block, two-stage MFMA (stage1 recomputes the
//   pm row each arm's loc points at; stage2 is the robot GEMM).
// Weights are converted fp32->bf16 in-register (no prep dispatch).
__global__ __launch_bounds__(256) void fused_kernel(
    const float* __restrict__ enc_row,   // [B,N,D]
    const float* __restrict__ enc_col,   // [B,S,D]
    const float* __restrict__ clockp,    // [B]
    const float* __restrict__ lpet,      // [B,P]
    const float* __restrict__ W_dyn,     // [2,D]
    const float* __restrict__ Wc,        // W_concat [K,D] fp32
    const float* __restrict__ Wr,        // W_robot  [K,D] fp32
    const int*   __restrict__ lhw,       // [B,P]
    const int*   __restrict__ lstage,    // [B,P]
    const int* __restrict__ loc1, const int* __restrict__ loc2,
    const int* __restrict__ rec1, const int* __restrict__ rec2,
    const int* __restrict__ nst1, const int* __restrict__ nst2,
    float* __restrict__ out)             // [B,P+2,D]
{
    __shared__ uint32_t xs[32 * ROWPAD];   // 24.5 KB: pm 32 rows / arm 16+16
    __shared__ int locs[16];

    const int lane = threadIdx.x & 63;
    const int wave = threadIdx.x >> 6;
    const int q = lane >> 4;
    const int n16 = lane & 15;
    const int t0 = wave * 2, t1 = t0 + 1;
    const float2 wd = ((const float2*)W_dyn)[lane];  // W_dyn row 0 (purge = 0)

    if (blockIdx.x < PM_BLOCKS) {
        // ================= pm path: 32 rows =================
        const int r0 = blockIdx.x * 32;              // rid = b*P + p
        #pragma unroll
        for (int rr = 0; rr < 8; ++rr) {
            const int r = wave * 8 + rr;
            const int rid = r0 + r;
            const int b = rid >> 6;                  // P == 64
            const float c = clockp[b];
            const float tt = lpet[rid];
            const float rem = (tt > c) ? (tt - c) * (1.0f / 300.0f) : 0.0f;
            const int wi = lhw[rid];
            const int cs = lstage[rid] - 1;
            const float2 sv = ((const float2*)(enc_col + ((size_t)b * S + cs) * D))[lane];
            float2 wv = make_float2(0.f, 0.f);
            if (wi >= 0)
                wv = ((const float2*)(enc_row + ((size_t)b * N + wi) * D))[lane];
            xs[r * ROWPAD + 0 * 64 + lane] = pack2(sv.x, sv.y);
            xs[r * ROWPAD + 1 * 64 + lane] = pack2(wv.x, wv.y);
            xs[r * ROWPAD + 2 * 64 + lane] = pack2(wd.x * rem, wd.y * rem);
        }
        __syncthreads();

        f32x4 acc00 = {0.f, 0.f, 0.f, 0.f};   // [m-tile][n-tile]
        f32x4 acc01 = {0.f, 0.f, 0.f, 0.f};
        f32x4 acc10 = {0.f, 0.f, 0.f, 0.f};
        f32x4 acc11 = {0.f, 0.f, 0.f, 0.f};
        #pragma unroll
        for (int ks = 0; ks < KS; ++ks) {
            const short8 a0 = *(const short8*)(xs + n16 * ROWPAD + ks * 16 + q * 4);
            const short8 a1 = *(const short8*)(xs + (16 + n16) * ROWPAD + ks * 16 + q * 4);
            const short8 b0 = load_bfrag(Wc, ks, q, t0 * 16 + n16);
            const short8 b1 = load_bfrag(Wc, ks, q, t1 * 16 + n16);
            acc00 = __builtin_amdgcn_mfma_f32_16x16x32_bf16(a0, b0, acc00, 0, 0, 0);
            acc01 = __builtin_amdgcn_mfma_f32_16x16x32_bf16(a0, b1, acc01, 0, 0, 0);
            acc10 = __builtin_amdgcn_mfma_f32_16x16x32_bf16(a1, b0, acc10, 0, 0, 0);
            acc11 = __builtin_amdgcn_mfma_f32_16x16x32_bf16(a1, b1, acc11, 0, 0, 0);
        }
        #pragma unroll
        for (int i = 0; i < 4; ++i) {
            #pragma unroll
            for (int mt = 0; mt < 2; ++mt) {
                const int row = mt * 16 + q * 4 + i;
                const int rid = r0 + row;
                const int bb = rid >> 6;
                const int pp = rid & 63;
                float* o = out + ((size_t)bb * (P + 2) + pp) * D;
                o[t0 * 16 + n16] = mt ? acc10[i] : acc00[i];
                o[t1 * 16 + n16] = mt ? acc11[i] : acc01[i];
            }
        }
    } else {
        // ================= arm path: 16 instances =================
        const int ab = blockIdx.x - PM_BLOCKS;
        uint32_t* xs2 = xs + 16 * ROWPAD;            // rows 16..31 alias
        #pragma unroll
        for (int rr = 0; rr < 4; ++rr) {
            const int r = wave * 4 + rr;
            const int aid = ab * 16 + r;             // 0..255
            const int b = aid >> 1;
            const int arm = aid & 1;
            const int loc = arm ? loc2[b] : loc1[b];
            const int rec = arm ? rec2[b] : rec1[b];
            int ns = arm ? nst2[b] : nst1[b];
            if (ns < 0) ns = 0;
            if (lane == 0) locs[r] = loc;

            // stage-1 activation (recompute pm row loc-1) when loc in [1,P]
            if (loc >= 1 && loc <= P) {
                const int rid = b * P + (loc - 1);
                const float c = clockp[b];
                const float tt = lpet[rid];
                const float rem = (tt > c) ? (tt - c) * (1.0f / 300.0f) : 0.0f;
                const int wi = lhw[rid];
                const int cs = lstage[rid] - 1;
                const float2 sv = ((const float2*)(enc_col + ((size_t)b * S + cs) * D))[lane];
                float2 wv = make_float2(0.f, 0.f);
                if (wi >= 0)
                    wv = ((const float2*)(enc_row + ((size_t)b * N + wi) * D))[lane];
                xs[r * ROWPAD + 0 * 64 + lane] = pack2(sv.x, sv.y);
                xs[r * ROWPAD + 1 * 64 + lane] = pack2(wv.x, wv.y);
                xs[r * ROWPAD + 2 * 64 + lane] = pack2(wd.x * rem, wd.y * rem);
            } else {
                xs[r * ROWPAD + 0 * 64 + lane] = 0u;
                xs[r * ROWPAD + 1 * 64 + lane] = 0u;
                xs[r * ROWPAD + 2 * 64 + lane] = 0u;
            }

            // stage-2 gathered segments: a_wafer (cols 128..255), a_ns (256..383)
            float2 awv = make_float2(0.f, 0.f);
            if (rec >= 0)
                awv = ((const float2*)(enc_row + ((size_t)b * N + rec) * D))[lane];
            float2 anv = make_float2(0.f, 0.f);
            if (ns >= 1 && ns <= S)
                anv = ((const float2*)(enc_col + ((size_t)b * S + (ns - 1)) * D))[lane];
            xs2[r * ROWPAD + 1 * 64 + lane] = pack2(awv.x, awv.y);
            xs2[r * ROWPAD + 2 * 64 + lane] = pack2(anv.x, anv.y);
        }
        __syncthreads();

        // stage-1 MFMA: recompute pm rows (16 x 128)
        f32x4 acc0 = {0.f, 0.f, 0.f, 0.f};
        f32x4 acc1 = {0.f, 0.f, 0.f, 0.f};
        #pragma unroll
        for (int ks = 0; ks < KS; ++ks) {
            const short8 a = *(const short8*)(xs + n16 * ROWPAD + ks * 16 + q * 4);
            const short8 b0 = load_bfrag(Wc, ks, q, t0 * 16 + n16);
            const short8 b1 = load_bfrag(Wc, ks, q, t1 * 16 + n16);
            acc0 = __builtin_amdgcn_mfma_f32_16x16x32_bf16(a, b0, acc0, 0, 0, 0);
            acc1 = __builtin_amdgcn_mfma_f32_16x16x32_bf16(a, b1, acc1, 0, 0, 0);
        }

        // a_loc into stage-2 activation cols 0..127 (bf16), with loc==0 -> 0,
        // loc==P+1 -> 1.0 overrides. Writes rows 16..31 — disjoint from stage-1
        // reads (rows 0..15) and per-wave-disjoint short columns.
        unsigned short* u2 = (unsigned short*)xs2;
        #pragma unroll
        for (int i = 0; i < 4; ++i) {
            const int row = q * 4 + i;
            const int lc = locs[row];
            float v0 = acc0[i], v1 = acc1[i];
            if (lc == 0)      { v0 = 0.f; v1 = 0.f; }
            if (lc == P + 1)  { v0 = 1.f; v1 = 1.f; }
            u2[row * (2 * ROWPAD) + t0 * 16 + n16] = (unsigned short)f2bf(v0);
            u2[row * (2 * ROWPAD) + t1 * 16 + n16] = (unsigned short)f2bf(v1);
        }
        __syncthreads();

        // stage-2 MFMA: robot GEMM
        f32x4 racc0 = {0.f, 0.f, 0.f, 0.f};
        f32x4 racc1 = {0.f, 0.f, 0.f, 0.f};
        #pragma unroll
        for (int ks = 0; ks < KS; ++ks) {
            const short8 a = *(const short8*)(xs2 + n16 * ROWPAD + ks * 16 + q * 4);
            const short8 b0 = load_bfrag(Wr, ks, q, t0 * 16 + n16);
            const short8 b1 = load_bfrag(Wr, ks, q, t1 * 16 + n16);
            racc0 = __builtin_amdgcn_mfma_f32_16x16x32_bf16(a, b0, racc0, 0, 0, 0);
            racc1 = __builtin_amdgcn_mfma_f32_16x16x32_bf16(a, b1, racc1, 0, 0, 0);
        }
        #pragma unroll
        for (int i = 0; i < 4; ++i) {
            const int row = q * 4 + i;
            const int aid = ab * 16 + row;
            const int bb = aid >> 1;
            const int arm = aid & 1;
            float* o = out + ((size_t)bb * (P + 2) + P + arm) * D;
            o[t0 * 16 + n16] = racc0[i];
            o[t1 * 16 + n16] = racc1[i];
        }
    }
}

extern "C" void kernel_launch(void* const* d_in, const int* in_sizes, int n_in,
                              void* d_out, int out_size, void* d_ws, size_t ws_size,
                              hipStream_t stream) {
    const float* enc_row  = (const float*)d_in[0];
    const float* enc_col  = (const float*)d_in[1];
    const float* clockp   = (const float*)d_in[2];
    const float* lpet     = (const float*)d_in[3];
    const float* W_dyn    = (const float*)d_in[4];
    const float* W_concat = (const float*)d_in[5];
    const float* W_robot  = (const float*)d_in[6];
    const int*   lhw      = (const int*)d_in[7];
    const int*   lstage   = (const int*)d_in[8];
    const int*   loc1     = (const int*)d_in[9];
    const int*   loc2     = (const int*)d_in[10];
    const int*   rec1     = (const int*)d_in[11];
    const int*   rec2     = (const int*)d_in[12];
    const int*   nst1     = (const int*)d_in[13];
    const int*   nst2     = (const int*)d_in[14];
    float* out = (float*)d_out;
    (void)d_ws; (void)ws_size;           // no workspace needed anymore

    fused_kernel<<<PM_BLOCKS + ARM_BLOCKS, 256, 0, stream>>>(
        enc_row, enc_col, clockp, lpet, W_dyn, W_concat, W_robot, lhw, lstage,
        loc1, loc2, rec1, rec2, nst1, nst2, out);
}